// Round 1
// baseline (1504.808 us; speedup 1.0000x reference)
//
#include <hip/hip_runtime.h>
#include <hip/hip_bf16.h>

#define NS 512
#define NV 32000
#define NB 16
#define NT 128

// ---------------------------------------------------------------------------
// K1: per-state logZ over vocab (logsumexp, no max needed: em ~ N(0,1)) fused
// with the emission gather: em_tok[j=b*T+t][s] = em[s, ids[j]] - logZ[s].
// grid = 512 blocks (one per state row), 256 threads.
// ---------------------------------------------------------------------------
__global__ __launch_bounds__(256) void k_emtok(
    const float* __restrict__ em, const int* __restrict__ ids,
    float* __restrict__ em_tok)
{
    const int s   = blockIdx.x;
    const int tid = threadIdx.x;
    const float* row = em + (size_t)s * NV;

    // 32000 = 31*256*4 + 256 : float4 part then one scalar each
    float sum = 0.f;
    const float4* row4 = (const float4*)row;
#pragma unroll 4
    for (int i = 0; i < 31; ++i) {
        float4 v = row4[tid + 256 * i];
        sum += __expf(v.x) + __expf(v.y) + __expf(v.z) + __expf(v.w);
    }
    sum += __expf(row[31744 + tid]);

#pragma unroll
    for (int off = 32; off; off >>= 1) sum += __shfl_down(sum, off);
    __shared__ float red[4];
    __shared__ float s_logZ;
    if ((tid & 63) == 0) red[tid >> 6] = sum;
    __syncthreads();
    if (tid == 0) s_logZ = __logf(((red[0] + red[1]) + (red[2] + red[3])));
    __syncthreads();
    const float logZ = s_logZ;

    // gather: row data is hot in L2 (just streamed by this block)
    for (int j = tid; j < NB * NT; j += 256) {
        em_tok[(size_t)j * NS + s] = row[ids[j]] - logZ;
    }
}

// ---------------------------------------------------------------------------
// K2: P[k][d] = softmax(tm[k,:])[d] stored as bf16, row-major [512][512].
// grid = 512 blocks (one per source row), 64 threads (one wave).
// ---------------------------------------------------------------------------
__global__ __launch_bounds__(64) void k_trans(
    const float* __restrict__ tm, __hip_bfloat16* __restrict__ P)
{
    const int k    = blockIdx.x;
    const int lane = threadIdx.x;
    const float* row = tm + (size_t)k * NS;

    float4 a = ((const float4*)row)[lane * 2];
    float4 b = ((const float4*)row)[lane * 2 + 1];
    float e0 = __expf(a.x), e1 = __expf(a.y), e2 = __expf(a.z), e3 = __expf(a.w);
    float e4 = __expf(b.x), e5 = __expf(b.y), e6 = __expf(b.z), e7 = __expf(b.w);
    float sum = ((e0 + e1) + (e2 + e3)) + ((e4 + e5) + (e6 + e7));
#pragma unroll
    for (int off = 32; off; off >>= 1) sum += __shfl_down(sum, off);
    sum = __shfl(sum, 0);
    const float inv = 1.f / sum;

    __hip_bfloat16* o = P + (size_t)k * NS + lane * 8;
    o[0] = __float2bfloat16(e0 * inv);
    o[1] = __float2bfloat16(e1 * inv);
    o[2] = __float2bfloat16(e2 * inv);
    o[3] = __float2bfloat16(e3 * inv);
    o[4] = __float2bfloat16(e4 * inv);
    o[5] = __float2bfloat16(e5 * inv);
    o[6] = __float2bfloat16(e6 * inv);
    o[7] = __float2bfloat16(e7 * inv);
}

// ---------------------------------------------------------------------------
// K3: the forward scan. One block per batch element (16 blocks, no cross-block
// sync needed). 512 threads: thread d owns destination state d.
// alpha lives in a register (only the owner ever reads it); exp(alpha-m) is
// shared via LDS. P is re-streamed from L2 each step (the known bottleneck of
// this baseline — to be replaced by register-resident fp8 MFMA).
// ---------------------------------------------------------------------------
__global__ __launch_bounds__(512) void k_scan(
    const float* __restrict__ em_tok, const __hip_bfloat16* __restrict__ P,
    const float* __restrict__ p, float* __restrict__ out)
{
    const int b   = blockIdx.x;
    const int tid = threadIdx.x;
    __shared__ float ebuf[NS];
    __shared__ float red[8];
    __shared__ float bval;

    const float* et = em_tok + (size_t)b * NT * NS;

    // prior log-softmax denominator (cheap, done redundantly per block)
    {
        float ps = __expf(p[tid]);
#pragma unroll
        for (int off = 32; off; off >>= 1) ps += __shfl_down(ps, off);
        if ((tid & 63) == 0) red[tid >> 6] = ps;
        __syncthreads();
        if (tid == 0) {
            float t = 0.f;
#pragma unroll
            for (int i = 0; i < 8; ++i) t += red[i];
            bval = __logf(t);
        }
        __syncthreads();
    }
    float a_reg = p[tid] - bval + et[tid];   // alpha_0[tid]
    __syncthreads();                          // protect red/bval reuse

    for (int t = 1; t < NT; ++t) {
        // ---- m_b = max over states ----
        float m = a_reg;
#pragma unroll
        for (int off = 32; off; off >>= 1) m = fmaxf(m, __shfl_down(m, off));
        if ((tid & 63) == 0) red[tid >> 6] = m;
        __syncthreads();
        if (tid == 0) {
            float mm = red[0];
#pragma unroll
            for (int i = 1; i < 8; ++i) mm = fmaxf(mm, red[i]);
            bval = mm;
        }
        __syncthreads();
        const float mb = bval;

        // ---- e = exp(alpha - m) shared across the block ----
        ebuf[tid] = __expf(a_reg - mb);
        __syncthreads();

        // ---- y[d] = sum_src e[src] * P[src][d]  (coalesced bf16 column) ----
        float acc = 0.f;
        const __hip_bfloat16* Pd = P + tid;
#pragma unroll 1
        for (int src = 0; src < NS; src += 8) {
            float c0 = __bfloat162float(Pd[(size_t)(src + 0) * NS]);
            float c1 = __bfloat162float(Pd[(size_t)(src + 1) * NS]);
            float c2 = __bfloat162float(Pd[(size_t)(src + 2) * NS]);
            float c3 = __bfloat162float(Pd[(size_t)(src + 3) * NS]);
            float c4 = __bfloat162float(Pd[(size_t)(src + 4) * NS]);
            float c5 = __bfloat162float(Pd[(size_t)(src + 5) * NS]);
            float c6 = __bfloat162float(Pd[(size_t)(src + 6) * NS]);
            float c7 = __bfloat162float(Pd[(size_t)(src + 7) * NS]);
            acc += ebuf[src + 0] * c0;
            acc += ebuf[src + 1] * c1;
            acc += ebuf[src + 2] * c2;
            acc += ebuf[src + 3] * c3;
            acc += ebuf[src + 4] * c4;
            acc += ebuf[src + 5] * c5;
            acc += ebuf[src + 6] * c6;
            acc += ebuf[src + 7] * c7;
        }

        a_reg = mb + __logf(acc) + et[(size_t)t * NS + tid];
        __syncthreads();   // all ebuf reads done before next overwrite
    }

    // ---- loss contribution: -logsumexp_s(alpha_T) / NB ----
    float m = a_reg;
#pragma unroll
    for (int off = 32; off; off >>= 1) m = fmaxf(m, __shfl_down(m, off));
    if ((tid & 63) == 0) red[tid >> 6] = m;
    __syncthreads();
    if (tid == 0) {
        float mm = red[0];
#pragma unroll
        for (int i = 1; i < 8; ++i) mm = fmaxf(mm, red[i]);
        bval = mm;
    }
    __syncthreads();
    const float M = bval;
    __syncthreads();
    float es = __expf(a_reg - M);
#pragma unroll
    for (int off = 32; off; off >>= 1) es += __shfl_down(es, off);
    if ((tid & 63) == 0) red[tid >> 6] = es;
    __syncthreads();
    if (tid == 0) {
        float ssum = 0.f;
#pragma unroll
        for (int i = 0; i < 8; ++i) ssum += red[i];
        atomicAdd(out, -(M + __logf(ssum)) * (1.0f / NB));
    }
}

// ---------------------------------------------------------------------------
extern "C" void kernel_launch(void* const* d_in, const int* in_sizes, int n_in,
                              void* d_out, int out_size, void* d_ws, size_t ws_size,
                              hipStream_t stream)
{
    const int*   ids = (const int*)d_in[0];   // [16][128]
    const float* em  = (const float*)d_in[1]; // [512][32000]
    const float* tm  = (const float*)d_in[2]; // [512][512]
    const float* p   = (const float*)d_in[3]; // [512]
    float* out = (float*)d_out;

    float* em_tok = (float*)d_ws;                                  // 4 MB: [2048][512] f32
    __hip_bfloat16* P = (__hip_bfloat16*)((char*)d_ws + (size_t)4 * 1024 * 1024); // 512 KB

    hipMemsetAsync(d_out, 0, sizeof(float), stream);

    k_emtok<<<NS, 256, 0, stream>>>(em, ids, em_tok);
    k_trans<<<NS, 64, 0, stream>>>(tm, P);
    k_scan<<<NB, 512, 0, stream>>>(em_tok, P, p, out);
}

// Round 2
// 697.755 us; speedup vs baseline: 2.1566x; 2.1566x over previous
//
#include <hip/hip_runtime.h>
#include <hip/hip_bf16.h>

#define NS 512
#define NV 32000
#define NB 16
#define NT 128

// ---------------------------------------------------------------------------
// K1: per-state logZ over vocab (logsumexp, no max needed: em ~ N(0,1)) fused
// with the emission gather: em_tok[j=b*T+t][s] = em[s, ids[j]] - logZ[s].
// grid = 512 blocks (one per state row), 256 threads.
// ---------------------------------------------------------------------------
__global__ __launch_bounds__(256) void k_emtok(
    const float* __restrict__ em, const int* __restrict__ ids,
    float* __restrict__ em_tok)
{
    const int s   = blockIdx.x;
    const int tid = threadIdx.x;
    const float* row = em + (size_t)s * NV;

    // 32000 = 31*256*4 + 256 : float4 part then one scalar each
    float sum = 0.f;
    const float4* row4 = (const float4*)row;
#pragma unroll 4
    for (int i = 0; i < 31; ++i) {
        float4 v = row4[tid + 256 * i];
        sum += __expf(v.x) + __expf(v.y) + __expf(v.z) + __expf(v.w);
    }
    sum += __expf(row[31744 + tid]);

#pragma unroll
    for (int off = 32; off; off >>= 1) sum += __shfl_down(sum, off);
    __shared__ float red[4];
    __shared__ float s_logZ;
    if ((tid & 63) == 0) red[tid >> 6] = sum;
    __syncthreads();
    if (tid == 0) s_logZ = __logf(((red[0] + red[1]) + (red[2] + red[3])));
    __syncthreads();
    const float logZ = s_logZ;

    // gather: row data is hot in L2 (just streamed by this block)
    for (int j = tid; j < NB * NT; j += 256) {
        em_tok[(size_t)j * NS + s] = row[ids[j]] - logZ;
    }
}

// ---------------------------------------------------------------------------
// K2: P[k][d] = softmax(tm[k,:])[d] stored as bf16, row-major [512][512].
// grid = 512 blocks (one per source row), 64 threads (one wave).
// ---------------------------------------------------------------------------
__global__ __launch_bounds__(64) void k_trans(
    const float* __restrict__ tm, __hip_bfloat16* __restrict__ P)
{
    const int k    = blockIdx.x;
    const int lane = threadIdx.x;
    const float* row = tm + (size_t)k * NS;

    float4 a = ((const float4*)row)[lane * 2];
    float4 b = ((const float4*)row)[lane * 2 + 1];
    float e0 = __expf(a.x), e1 = __expf(a.y), e2 = __expf(a.z), e3 = __expf(a.w);
    float e4 = __expf(b.x), e5 = __expf(b.y), e6 = __expf(b.z), e7 = __expf(b.w);
    float sum = ((e0 + e1) + (e2 + e3)) + ((e4 + e5) + (e6 + e7));
#pragma unroll
    for (int off = 32; off; off >>= 1) sum += __shfl_down(sum, off);
    sum = __shfl(sum, 0);
    const float inv = 1.f / sum;

    __hip_bfloat16* o = P + (size_t)k * NS + lane * 8;
    o[0] = __float2bfloat16(e0 * inv);
    o[1] = __float2bfloat16(e1 * inv);
    o[2] = __float2bfloat16(e2 * inv);
    o[3] = __float2bfloat16(e3 * inv);
    o[4] = __float2bfloat16(e4 * inv);
    o[5] = __float2bfloat16(e5 * inv);
    o[6] = __float2bfloat16(e6 * inv);
    o[7] = __float2bfloat16(e7 * inv);
}

// ---------------------------------------------------------------------------
// K3: forward scan. One block per batch (16 blocks, zero cross-block sync),
// 1024 threads = 16 waves. Thread layout for the per-step matmul
//   y[d] = sum_src e[src] * P[src][d]:
//   d8 = tid & 63  -> owns dst states 8*d8 .. 8*d8+7
//   o  = tid >> 6  -> src group 32*o .. 32*o+31  (wave-uniform)
// Each thread: 32 x uint4 (8 bf16) loads of P, 1 KB contiguous per wave-instr.
// Partials combined via LDS part[16][512]. alpha stays in registers of
// threads 0..511; only exp(alpha - m) goes through LDS.
// ---------------------------------------------------------------------------
__global__ __launch_bounds__(1024) void k_scan(
    const float* __restrict__ em_tok, const __hip_bfloat16* __restrict__ P,
    const float* __restrict__ p, float* __restrict__ out)
{
    const int b   = blockIdx.x;
    const int tid = threadIdx.x;
    const int d8  = tid & 63;
    const int o   = tid >> 6;

    __shared__ float ebuf[NS];
    __shared__ float part[16][NS];
    __shared__ float red[8];

    const float* et = em_tok + (size_t)b * NT * NS;

    float a = 0.f;   // alpha[tid], valid for tid < 512

    // ---- prior log-softmax Z (redundant per block, trivial) ----
    if (tid < NS) {
        float ps = __expf(p[tid]);
#pragma unroll
        for (int off = 32; off; off >>= 1) ps += __shfl_down(ps, off);
        if ((tid & 63) == 0) red[tid >> 6] = ps;
    }
    __syncthreads();
    {
        float z = ((red[0] + red[1]) + (red[2] + red[3]))
                + ((red[4] + red[5]) + (red[6] + red[7]));
        if (tid < NS) a = p[tid] - __logf(z) + et[tid];
    }
    __syncthreads();   // red reuse guard

    const __hip_bfloat16* Pb = P + (size_t)(o * 32) * NS + 8 * d8;

    for (int t = 1; t < NT; ++t) {
        // ---- phase 1: per-wave max of alpha (waves 0..7) ----
        if (tid < NS) {
            float m = a;
#pragma unroll
            for (int off = 32; off; off >>= 1) m = fmaxf(m, __shfl_down(m, off));
            if ((tid & 63) == 0) red[tid >> 6] = m;
        }
        __syncthreads();                           // S1
        const float mb = fmaxf(fmaxf(fmaxf(red[0], red[1]), fmaxf(red[2], red[3])),
                               fmaxf(fmaxf(red[4], red[5]), fmaxf(red[6], red[7])));
        float enext = 0.f;
        if (tid < NS) {
            ebuf[tid] = __expf(a - mb);
            enext = et[(size_t)t * NS + tid];      // prefetch; hides under matmul
        }
        __syncthreads();                           // S2

        // ---- phase 2: y = e . P, 8 dst per thread, 32 src per thread ----
        float acc0 = 0.f, acc1 = 0.f, acc2 = 0.f, acc3 = 0.f;
        float acc4 = 0.f, acc5 = 0.f, acc6 = 0.f, acc7 = 0.f;
        const float* eb = &ebuf[o * 32];
#pragma unroll 8
        for (int k = 0; k < 32; ++k) {
            uint4 raw = *(const uint4*)(Pb + (size_t)k * NS);
            float e = eb[k];
            acc0 = fmaf(e, __uint_as_float(raw.x << 16),          acc0);
            acc1 = fmaf(e, __uint_as_float(raw.x & 0xffff0000u),  acc1);
            acc2 = fmaf(e, __uint_as_float(raw.y << 16),          acc2);
            acc3 = fmaf(e, __uint_as_float(raw.y & 0xffff0000u),  acc3);
            acc4 = fmaf(e, __uint_as_float(raw.z << 16),          acc4);
            acc5 = fmaf(e, __uint_as_float(raw.z & 0xffff0000u),  acc5);
            acc6 = fmaf(e, __uint_as_float(raw.w << 16),          acc6);
            acc7 = fmaf(e, __uint_as_float(raw.w & 0xffff0000u),  acc7);
        }
        float4* pr = (float4*)&part[o][8 * d8];
        pr[0] = make_float4(acc0, acc1, acc2, acc3);
        pr[1] = make_float4(acc4, acc5, acc6, acc7);
        __syncthreads();                           // S3

        // ---- phase 3: fold 16 src-groups, update alpha ----
        if (tid < NS) {
            float y = 0.f;
#pragma unroll
            for (int i = 0; i < 16; ++i) y += part[i][tid];
            a = mb + __logf(y) + enext;
        }
    }

    // ---- final: -logsumexp_s(alpha_T) / NB ----
    if (tid < NS) {
        float m = a;
#pragma unroll
        for (int off = 32; off; off >>= 1) m = fmaxf(m, __shfl_down(m, off));
        if ((tid & 63) == 0) red[tid >> 6] = m;
    }
    __syncthreads();
    const float M = fmaxf(fmaxf(fmaxf(red[0], red[1]), fmaxf(red[2], red[3])),
                          fmaxf(fmaxf(red[4], red[5]), fmaxf(red[6], red[7])));
    __syncthreads();
    if (tid < NS) {
        float es = __expf(a - M);
#pragma unroll
        for (int off = 32; off; off >>= 1) es += __shfl_down(es, off);
        if ((tid & 63) == 0) red[tid >> 6] = es;
    }
    __syncthreads();
    if (tid == 0) {
        float s = ((red[0] + red[1]) + (red[2] + red[3]))
                + ((red[4] + red[5]) + (red[6] + red[7]));
        atomicAdd(out, -(M + __logf(s)) * (1.0f / NB));
    }
}

// ---------------------------------------------------------------------------
extern "C" void kernel_launch(void* const* d_in, const int* in_sizes, int n_in,
                              void* d_out, int out_size, void* d_ws, size_t ws_size,
                              hipStream_t stream)
{
    const int*   ids = (const int*)d_in[0];   // [16][128]
    const float* em  = (const float*)d_in[1]; // [512][32000]
    const float* tm  = (const float*)d_in[2]; // [512][512]
    const float* p   = (const float*)d_in[3]; // [512]
    float* out = (float*)d_out;

    float* em_tok = (float*)d_ws;                                  // 4 MB: [2048][512] f32
    __hip_bfloat16* P = (__hip_bfloat16*)((char*)d_ws + (size_t)4 * 1024 * 1024); // 512 KB

    hipMemsetAsync(d_out, 0, sizeof(float), stream);

    k_emtok<<<NS, 256, 0, stream>>>(em, ids, em_tok);
    k_trans<<<NS, 64, 0, stream>>>(tm, P);
    k_scan<<<NB, 1024, 0, stream>>>(em_tok, P, p, out);
}

// Round 3
// 295.742 us; speedup vs baseline: 5.0882x; 2.3593x over previous
//
#include <hip/hip_runtime.h>
#include <hip/hip_bf16.h>

#define NS 512
#define NV 32000
#define NB 16
#define NT 128

#ifndef __has_builtin
#define __has_builtin(x) 0
#endif

typedef int v8i __attribute__((ext_vector_type(8)));
typedef float v4f __attribute__((ext_vector_type(4)));

// ---------------------------------------------------------------------------
// e4m3fn (OCP) encode, x >= 0. Used as fallback / in setup kernels.
// ---------------------------------------------------------------------------
__device__ inline unsigned enc_e4m3(float x) {
    x = fminf(x, 448.0f);
    unsigned u = __float_as_uint(x);
    if (x < 0.015625f) {                       // subnormal: round(x * 2^9)
        return (unsigned)(int)rintf(x * 512.0f);
    }
    unsigned u2 = u + 0x7FFFFu + ((u >> 20) & 1u);   // RNE to 3 mantissa bits
    return (((u2 >> 23) - 120u) << 3) | ((u2 >> 20) & 7u);
}

__device__ inline unsigned pack4_e4m3(float a, float b, float c, float d) {
#if __has_builtin(__builtin_amdgcn_cvt_pk_fp8_f32)
    int v = __builtin_amdgcn_cvt_pk_fp8_f32(a, b, 0, false);
    v = __builtin_amdgcn_cvt_pk_fp8_f32(c, d, v, true);
    return (unsigned)v;
#else
    return enc_e4m3(a) | (enc_e4m3(b) << 8) | (enc_e4m3(c) << 16) | (enc_e4m3(d) << 24);
#endif
}

// DPP helpers (row = 16 lanes). bound_ctrl=1 -> out-of-row sources read 0.
// Safe: max operands are >0 (linear-domain alpha), add with 0 is exact.
#define DPPMAX(x, ctrl) \
    x = fmaxf(x, __int_as_float(__builtin_amdgcn_mov_dpp(__float_as_int(x), ctrl, 0xF, 0xF, true)))
#define DPPADD(x, ctrl) \
    x = x + __int_as_float(__builtin_amdgcn_mov_dpp(__float_as_int(x), ctrl, 0xF, 0xF, true))

// ---------------------------------------------------------------------------
// K1a: per-state logZ over vocab fused with emission gather, COALESCED store
// to em_lin_T[s][j] = exp(em[s][ids_j]) / Z_s * 2^-18  (linear domain).
// grid = 512 (one per state), 256 threads.
// ---------------------------------------------------------------------------
__global__ __launch_bounds__(256) void k_emtok_T(
    const float* __restrict__ em, const int* __restrict__ ids,
    float* __restrict__ em_lin_T)
{
    const int s   = blockIdx.x;
    const int tid = threadIdx.x;
    const float* row = em + (size_t)s * NV;

    float sum = 0.f;
    const float4* row4 = (const float4*)row;
#pragma unroll 4
    for (int i = 0; i < 31; ++i) {
        float4 v = row4[tid + 256 * i];
        sum += __expf(v.x) + __expf(v.y) + __expf(v.z) + __expf(v.w);
    }
    sum += __expf(row[31744 + tid]);

#pragma unroll
    for (int off = 32; off; off >>= 1) sum += __shfl_down(sum, off);
    __shared__ float red[4];
    __shared__ float s_scale;
    if ((tid & 63) == 0) red[tid >> 6] = sum;
    __syncthreads();
    if (tid == 0) s_scale = (1.0f / ((red[0] + red[1]) + (red[2] + red[3]))) * 0x1p-18f;
    __syncthreads();
    const float scale = s_scale;

    for (int j = tid; j < NB * NT; j += 256) {
        em_lin_T[(size_t)s * (NB * NT) + j] = __expf(row[ids[j]]) * scale;
    }
}

// Fallback (small workspace): strided store directly to em_lin[j][s].
__global__ __launch_bounds__(256) void k_emtok_direct(
    const float* __restrict__ em, const int* __restrict__ ids,
    float* __restrict__ em_lin)
{
    const int s   = blockIdx.x;
    const int tid = threadIdx.x;
    const float* row = em + (size_t)s * NV;

    float sum = 0.f;
    const float4* row4 = (const float4*)row;
#pragma unroll 4
    for (int i = 0; i < 31; ++i) {
        float4 v = row4[tid + 256 * i];
        sum += __expf(v.x) + __expf(v.y) + __expf(v.z) + __expf(v.w);
    }
    sum += __expf(row[31744 + tid]);
#pragma unroll
    for (int off = 32; off; off >>= 1) sum += __shfl_down(sum, off);
    __shared__ float red[4];
    __shared__ float s_scale;
    if ((tid & 63) == 0) red[tid >> 6] = sum;
    __syncthreads();
    if (tid == 0) s_scale = (1.0f / ((red[0] + red[1]) + (red[2] + red[3]))) * 0x1p-18f;
    __syncthreads();
    const float scale = s_scale;
    for (int j = tid; j < NB * NT; j += 256) {
        em_lin[(size_t)j * NS + s] = __expf(row[ids[j]]) * scale;
    }
}

// ---------------------------------------------------------------------------
// K1b: transpose em_lin_T [512][2048] -> em_lin [2048][512] (f32, 32x32 tiles)
// grid = (2048/32, 512/32) = (64,16), 256 threads.
// ---------------------------------------------------------------------------
__global__ __launch_bounds__(256) void k_tr(
    const float* __restrict__ emT, float* __restrict__ em_lin)
{
    __shared__ float tile[32][33];
    const int jb = blockIdx.x * 32;
    const int sb = blockIdx.y * 32;
    const int cc = threadIdx.x & 31;
    const int rr = threadIdx.x >> 5;
#pragma unroll
    for (int i = 0; i < 4; ++i) {
        int r = rr + 8 * i;
        tile[r][cc] = emT[(size_t)(sb + r) * (NB * NT) + jb + cc];
    }
    __syncthreads();
#pragma unroll
    for (int i = 0; i < 4; ++i) {
        int r = rr + 8 * i;
        em_lin[(size_t)(jb + r) * NS + sb + cc] = tile[cc][r];
    }
}

// ---------------------------------------------------------------------------
// K2: PT[d][k] = softmax(tm[k,:])[d] * 1024, e4m3 fp8, TRANSPOSED [dst][src].
// grid = 512 (one per source row), 64 threads.
// ---------------------------------------------------------------------------
__global__ __launch_bounds__(64) void k_pt(
    const float* __restrict__ tm, unsigned char* __restrict__ PT)
{
    const int k    = blockIdx.x;
    const int lane = threadIdx.x;
    const float* row = tm + (size_t)k * NS;

    float4 a = ((const float4*)row)[lane * 2];
    float4 b = ((const float4*)row)[lane * 2 + 1];
    float e0 = __expf(a.x), e1 = __expf(a.y), e2 = __expf(a.z), e3 = __expf(a.w);
    float e4 = __expf(b.x), e5 = __expf(b.y), e6 = __expf(b.z), e7 = __expf(b.w);
    float sum = ((e0 + e1) + (e2 + e3)) + ((e4 + e5) + (e6 + e7));
#pragma unroll
    for (int off = 32; off; off >>= 1) sum += __shfl_down(sum, off);
    sum = __shfl(sum, 0);
    const float sc = 1024.0f / sum;

    float ev[8] = {e0, e1, e2, e3, e4, e5, e6, e7};
#pragma unroll
    for (int i = 0; i < 8; ++i) {
        int d = lane * 8 + i;
        PT[(size_t)d * NS + k] = (unsigned char)(pack4_e4m3(ev[i] * sc, 0.f, 0.f, 0.f) & 0xFFu);
    }
}

// ---------------------------------------------------------------------------
// K3: the scan. ONE block, 512 threads (8 waves), all 16 batches as MFMA M.
//   - P fp8 held in VGPRs as B-fragments: wave w owns dst cols [64w, 64w+64)
//     -> B[nt][kt], nt in 0..3 (16-col tiles), kt in 0..3 (K=128 tiles).
//   - alpha linear-domain f32 in C-layout regs; per-batch pow2 rescale with
//     integer shift accumulator (no log/exp in the loop).
//   - E (16x512 fp8) through LDS, XOR-chunk-swizzled, DPP 4x4 byte transpose.
// ---------------------------------------------------------------------------
__global__ __launch_bounds__(512, 2) void k_scan(
    const float* __restrict__ em_lin, const unsigned char* __restrict__ PT,
    const float* __restrict__ p, float* __restrict__ out)
{
    const int tid = threadIdx.x;
    const int w   = tid >> 6;          // wave 0..7
    const int l   = tid & 63;          // lane
    const int lc  = l & 15;            // producer: state col in tile; consumer: m (batch)
    const int lq  = l >> 4;            // producer: batch quad; consumer: k quad

    __shared__ unsigned int Ew[2][16 * 128];   // 2 x 8 KB, [m][chunk^m swizzled]
    __shared__ float wm[16][8];
    __shared__ float mbuf[16];
    __shared__ int   sbuf[16];

    // ---- load B fragments (P, once) ----
    v8i B[4][4];
#pragma unroll
    for (int nt = 0; nt < 4; ++nt) {
#pragma unroll
        for (int kt = 0; kt < 4; ++kt) {
            const uint4* src = (const uint4*)(PT + (size_t)((w * 4 + nt) * 16 + lc) * NS + kt * 128 + lq * 32);
            uint4 lo = src[0], hi = src[1];
            v8i bb;
            bb[0] = (int)lo.x; bb[1] = (int)lo.y; bb[2] = (int)lo.z; bb[3] = (int)lo.w;
            bb[4] = (int)hi.x; bb[5] = (int)hi.y; bb[6] = (int)hi.z; bb[7] = (int)hi.w;
            B[nt][kt] = bb;
        }
    }

    // ---- prior softmax denominator (computed redundantly per wave) ----
    float zp = 0.f;
#pragma unroll
    for (int i = 0; i < 8; ++i) zp += __expf(p[l * 8 + i]);
    DPPADD(zp, 0x111); DPPADD(zp, 0x112); DPPADD(zp, 0x114); DPPADD(zp, 0x118);
    float Zp = __int_as_float(__builtin_amdgcn_readlane(__float_as_int(zp), 15))
             + __int_as_float(__builtin_amdgcn_readlane(__float_as_int(zp), 31))
             + __int_as_float(__builtin_amdgcn_readlane(__float_as_int(zp), 47))
             + __int_as_float(__builtin_amdgcn_readlane(__float_as_int(zp), 63));
    const float invZp = 1.0f / Zp;

    int dbase[4];
#pragma unroll
    for (int nt = 0; nt < 4; ++nt) dbase[nt] = (w * 4 + nt) * 16 + lc;

    // ---- alpha_0 (linear) ----
    float alpha[4][4];   // [nt][r], batch m = 4*lq + r, state d = dbase[nt]
#pragma unroll
    for (int nt = 0; nt < 4; ++nt) {
        float pl = __expf(p[dbase[nt]]) * invZp;
#pragma unroll
        for (int r = 0; r < 4; ++r)
            alpha[nt][r] = pl * em_lin[(4 * lq + r) * (NT * NS) + dbase[nt]];
    }

    int shift[4] = {0, 0, 0, 0};
    const unsigned sel1 = (l & 1) ? 0x07030501u : 0x02060004u;
    const unsigned sel2 = (l & 2) ? 0x07060302u : 0x01000504u;
    const int mrow = 4 * lq + (l & 3);       // row this lane writes after transpose

    for (int t = 1; t < NT; ++t) {
        // prefetch em_lin[:, t, :] (consumed at end of iteration)
        float epf[4][4];
#pragma unroll
        for (int nt = 0; nt < 4; ++nt)
#pragma unroll
            for (int r = 0; r < 4; ++r)
                epf[nt][r] = em_lin[(4 * lq + r) * (NT * NS) + t * NS + dbase[nt]];

        // ---- per-batch max (alpha > 0) ----
#pragma unroll
        for (int r = 0; r < 4; ++r) {
            float mx = fmaxf(fmaxf(alpha[0][r], alpha[1][r]), fmaxf(alpha[2][r], alpha[3][r]));
            DPPMAX(mx, 0x111); DPPMAX(mx, 0x112); DPPMAX(mx, 0x114); DPPMAX(mx, 0x118);
            if (lc == 15) wm[4 * lq + r][w] = mx;
        }
        __syncthreads();                                    // B1
        if (w == 0 && l < 16) {
            float4 a = *(const float4*)&wm[l][0];
            float4 b = *(const float4*)&wm[l][4];
            mbuf[l] = fmaxf(fmaxf(fmaxf(a.x, a.y), fmaxf(a.z, a.w)),
                            fmaxf(fmaxf(b.x, b.y), fmaxf(b.z, b.w)));
        }
        __syncthreads();                                    // B2
        float4 mb4 = *(const float4*)&mbuf[4 * lq];
        float mbv[4] = {mb4.x, mb4.y, mb4.z, mb4.w};
        float sc[4];
#pragma unroll
        for (int r = 0; r < 4; ++r) {
            int Eb = (int)(__float_as_uint(mbv[r]) >> 23);
            sc[r] = __uint_as_float((unsigned)(261 - Eb) << 23);  // 2^(7 - (Eb-127))
            shift[r] += Eb - 126;
        }
        // ---- e = alpha * sc -> fp8, 4x4 byte transpose (DPP), LDS write ----
#pragma unroll
        for (int nt = 0; nt < 4; ++nt) {
            unsigned dw = pack4_e4m3(alpha[nt][0] * sc[0], alpha[nt][1] * sc[1],
                                     alpha[nt][2] * sc[2], alpha[nt][3] * sc[3]);
            int tmp = __builtin_amdgcn_mov_dpp((int)dw, 0xB1, 0xF, 0xF, true);   // quad xor1
            dw = __builtin_amdgcn_perm(dw, (unsigned)tmp, sel1);
            tmp = __builtin_amdgcn_mov_dpp((int)dw, 0x4E, 0xF, 0xF, true);        // quad xor2
            dw = __builtin_amdgcn_perm(dw, (unsigned)tmp, sel2);
            int chunk = ((w * 4 + nt) ^ mrow) & 31;
            Ew[t & 1][mrow * 128 + chunk * 4 + (lc >> 2)] = dw;
        }
        __syncthreads();                                    // B3

        // ---- A fragments from LDS (swizzled) ----
        v8i A[4];
        const uint4* eb = (const uint4*)&Ew[t & 1][0];
#pragma unroll
        for (int kt = 0; kt < 4; ++kt) {
            uint4 lo = eb[lc * 32 + (((kt * 8 + lq * 2 + 0) ^ lc) & 31)];
            uint4 hi = eb[lc * 32 + (((kt * 8 + lq * 2 + 1) ^ lc) & 31)];
            v8i aa;
            aa[0] = (int)lo.x; aa[1] = (int)lo.y; aa[2] = (int)lo.z; aa[3] = (int)lo.w;
            aa[4] = (int)hi.x; aa[5] = (int)hi.y; aa[6] = (int)hi.z; aa[7] = (int)hi.w;
            A[kt] = aa;
        }

        // ---- MFMA: Y = E . P ----
        v4f C[4];
#pragma unroll
        for (int nt = 0; nt < 4; ++nt) { C[nt][0] = 0.f; C[nt][1] = 0.f; C[nt][2] = 0.f; C[nt][3] = 0.f; }
#pragma unroll
        for (int kt = 0; kt < 4; ++kt)
#pragma unroll
            for (int nt = 0; nt < 4; ++nt)
                C[nt] = __builtin_amdgcn_mfma_scale_f32_16x16x128_f8f6f4(
                            A[kt], B[nt][kt], C[nt], 0, 0, 0, 0x7F7F7F7F, 0, 0x7F7F7F7F);

        // ---- alpha update (linear) ----
#pragma unroll
        for (int nt = 0; nt < 4; ++nt)
#pragma unroll
            for (int r = 0; r < 4; ++r)
                alpha[nt][r] = C[nt][r] * epf[nt][r];
    }

    // ---- final: loss = -(ln2/16) * sum_b (log2(sum_d alpha) + shift_b) ----
#pragma unroll
    for (int r = 0; r < 4; ++r) {
        float sm = ((alpha[0][r] + alpha[1][r]) + (alpha[2][r] + alpha[3][r]));
        DPPADD(sm, 0x111); DPPADD(sm, 0x112); DPPADD(sm, 0x114); DPPADD(sm, 0x118);
        if (lc == 15) wm[4 * lq + r][w] = sm;
        if (w == 0 && lc == 0) sbuf[4 * lq + r] = shift[r];
    }
    __syncthreads();
    if (w == 0 && l < 16) {
        float4 a = *(const float4*)&wm[l][0];
        float4 b = *(const float4*)&wm[l][4];
        float s8 = ((a.x + a.y) + (a.z + a.w)) + ((b.x + b.y) + (b.z + b.w));
        float L2 = __log2f(s8) + (float)sbuf[l];
        DPPADD(L2, 0x111); DPPADD(L2, 0x112); DPPADD(L2, 0x114); DPPADD(L2, 0x118);
        if (l == 15) out[0] = -(0.693147180559945f / 16.0f) * L2;
    }
}

// ---------------------------------------------------------------------------
extern "C" void kernel_launch(void* const* d_in, const int* in_sizes, int n_in,
                              void* d_out, int out_size, void* d_ws, size_t ws_size,
                              hipStream_t stream)
{
    const int*   ids = (const int*)d_in[0];   // [16][128]
    const float* em  = (const float*)d_in[1]; // [512][32000]
    const float* tm  = (const float*)d_in[2]; // [512][512]
    const float* p   = (const float*)d_in[3]; // [512]
    float* out = (float*)d_out;

    // layout: em_lin [0,4M), PT [4M, 4M+256K), (emT [4.25M, 8.25M) if room)
    float*          em_lin = (float*)d_ws;
    unsigned char*  PT     = (unsigned char*)d_ws + ((size_t)4 << 20);
    float*          emT    = (float*)((unsigned char*)d_ws + ((size_t)4 << 20) + ((size_t)256 << 10));

    const bool big_ws = ws_size >= (((size_t)8 << 20) + ((size_t)512 << 10));

    if (big_ws) {
        k_emtok_T<<<NS, 256, 0, stream>>>(em, ids, emT);
        k_tr<<<dim3(64, 16), 256, 0, stream>>>(emT, em_lin);
    } else {
        k_emtok_direct<<<NS, 256, 0, stream>>>(em, ids, em_lin);
    }
    k_pt<<<NS, 64, 0, stream>>>(tm, PT);
    k_scan<<<1, 512, 0, stream>>>(em_lin, PT, p, out);
}